// Round 6
// baseline (500.472 us; speedup 1.0000x reference)
//
#include <hip/hip_runtime.h>

#define SEQ 8
#define DIM 16
#define FF 32
#define VOCAB 256

// ds_swizzle XOR butterfly on a float (src_lane = lane ^ T, T<8 stays within
// the 8-lane item group). BitMode offset = (xor<<10) | (or<<5) | and, and=0x1F.
#define SWZF(val, imm) __int_as_float(__builtin_amdgcn_ds_swizzle(__float_as_int(val), (imm)))

// ---------------------------------------------------------------------------
// Body v3: 2 threads per row (wave-level half split) -> 8192 waves (8/SIMD).
// Wave 2g+h handles row-group g (64 rows) with model-dim half h: dims
// [8h,8h+8), FFN slice [16h,16h+16). Half is wave-uniform so every weight
// address is wave-uniform (s_load + SGPR-operand v_fmac). Intra-row K/V
// exchange: ds_swizzle XOR. Cross-half merges: 4 LDS ping-pong exchanges.
// ---------------------------------------------------------------------------
__global__ __launch_bounds__(256, 8) void body_kernel(
    const int* __restrict__ x,
    const float* __restrict__ token_embed,
    const float* __restrict__ pos_embed,
    const float* __restrict__ Wq, const float* __restrict__ bq,
    const float* __restrict__ Wk, const float* __restrict__ bk,
    const float* __restrict__ Wv, const float* __restrict__ bv,
    const float* __restrict__ Wo, const float* __restrict__ bo,
    const float* __restrict__ W1, const float* __restrict__ b1,
    const float* __restrict__ W2, const float* __restrict__ b2,
    float* __restrict__ xout)
{
    __shared__ float4 sbuf[512];   // 8 KB exchange buffer

    const int tid  = threadIdx.x;
    const int wave = tid >> 6;
    const int lane = tid & 63;
    const int half = wave & 1;          // wave-uniform model-dim half
    const int rgrp = wave >> 1;         // row group 0/1
    const int n    = lane & 7;          // seq position
    const int il   = lane >> 3;         // item within wave 0..7

    const int h8  = half * 8;           // own model-dim base
    const int o8  = 8 - h8;             // other half base
    const int f16 = half * 16;          // own FFN base

    const int item = blockIdx.x * 16 + rgrp * 8 + il;
    const size_t row = (size_t)item * SEQ + n;

    // ---------------- embedding + positional (full 16 dims) ----------------
    float X[DIM];
    {
        const int idx = x[row];
        const float4* te = (const float4*)(token_embed + (size_t)idx * DIM);
        const float4* pe = (const float4*)(pos_embed + n * DIM);
        #pragma unroll
        for (int j = 0; j < 4; ++j) {
            float4 a = te[j];
            float4 p = pe[j];
            X[4*j+0] = a.x + p.x;
            X[4*j+1] = a.y + p.y;
            X[4*j+2] = a.z + p.z;
            X[4*j+3] = a.w + p.w;
        }
    }

    // ---------------- QKV for own 8 output dims ----------------
    float q8[8], k8[8], v8[8];
    #pragma unroll
    for (int j = 0; j < 8; ++j) {
        q8[j] = bq[h8 + j]; k8[j] = bk[h8 + j]; v8[j] = bv[h8 + j];
    }
    #pragma unroll
    for (int d = 0; d < DIM; ++d) {
        const float xd = X[d];
        #pragma unroll
        for (int j = 0; j < 8; ++j) {
            q8[j] += xd * Wq[d * DIM + h8 + j];
            k8[j] += xd * Wk[d * DIM + h8 + j];
            v8[j] += xd * Wv[d * DIM + h8 + j];
        }
    }

    // ---------------- partial scores via XOR butterfly ----------------
    float sp[SEQ];
    {
        float p = 0.f;
        #pragma unroll
        for (int j = 0; j < 8; ++j) p += q8[j] * k8[j];
        sp[0] = p;
    }
    #define SCORE_PHASE(T, IMM)                                   \
    {                                                             \
        float p = 0.f;                                            \
        _Pragma("unroll")                                         \
        for (int j = 0; j < 8; ++j) p += q8[j] * SWZF(k8[j], IMM);\
        sp[T] = p;                                                \
    }
    SCORE_PHASE(1, 0x041F)
    SCORE_PHASE(2, 0x081F)
    SCORE_PHASE(3, 0x0C1F)
    SCORE_PHASE(4, 0x101F)
    SCORE_PHASE(5, 0x141F)
    SCORE_PHASE(6, 0x181F)
    SCORE_PHASE(7, 0x1C1F)
    #undef SCORE_PHASE

    // ---------------- exchange score partials with partner wave ------------
    __syncthreads();
    sbuf[tid]       = float4{sp[0], sp[1], sp[2], sp[3]};
    sbuf[256 + tid] = float4{sp[4], sp[5], sp[6], sp[7]};
    __syncthreads();
    const float4 pa = sbuf[tid ^ 64];
    const float4 pb = sbuf[256 + (tid ^ 64)];

    float sc[SEQ];
    sc[0] = (sp[0] + pa.x) * 0.25f;
    sc[1] = (sp[1] + pa.y) * 0.25f;
    sc[2] = (sp[2] + pa.z) * 0.25f;
    sc[3] = (sp[3] + pa.w) * 0.25f;
    sc[4] = (sp[4] + pb.x) * 0.25f;
    sc[5] = (sp[5] + pb.y) * 0.25f;
    sc[6] = (sp[6] + pb.z) * 0.25f;
    sc[7] = (sp[7] + pb.w) * 0.25f;

    // ---------------- softmax (per thread, redundant across halves) --------
    float mx = sc[0];
    #pragma unroll
    for (int m = 1; m < SEQ; ++m) mx = fmaxf(mx, sc[m]);
    float w[SEQ];
    float sum = 0.f;
    #pragma unroll
    for (int m = 0; m < SEQ; ++m) { w[m] = __expf(sc[m] - mx); sum += w[m]; }
    const float inv = 1.0f / sum;
    #pragma unroll
    for (int m = 0; m < SEQ; ++m) w[m] *= inv;

    // ---------------- PV via XOR butterfly (own 8 dims) ----------------
    float at8[8];
    #pragma unroll
    for (int j = 0; j < 8; ++j) at8[j] = w[0] * v8[j];
    #define PV_PHASE(T, IMM)                                      \
    {                                                             \
        const float wt = w[T];                                    \
        _Pragma("unroll")                                         \
        for (int j = 0; j < 8; ++j) at8[j] += wt * SWZF(v8[j], IMM);\
    }
    PV_PHASE(1, 0x041F)
    PV_PHASE(2, 0x081F)
    PV_PHASE(3, 0x0C1F)
    PV_PHASE(4, 0x101F)
    PV_PHASE(5, 0x141F)
    PV_PHASE(6, 0x181F)
    PV_PHASE(7, 0x1C1F)
    #undef PV_PHASE

    // ---------------- exchange attn output halves ----------------
    __syncthreads();
    sbuf[tid]       = float4{at8[0], at8[1], at8[2], at8[3]};
    sbuf[256 + tid] = float4{at8[4], at8[5], at8[6], at8[7]};
    __syncthreads();
    const float4 oa = sbuf[tid ^ 64];
    const float4 ob = sbuf[256 + (tid ^ 64)];
    float atO[8] = {oa.x, oa.y, oa.z, oa.w, ob.x, ob.y, ob.z, ob.w};

    // ---------------- O projection + residual (own 8 output dims) ----------
    // Extract own-half X with compile-time indices (avoid dynamic reg index).
    float Xo[8];
    if (half == 0) {
        #pragma unroll
        for (int j = 0; j < 8; ++j) Xo[j] = X[j];
    } else {
        #pragma unroll
        for (int j = 0; j < 8; ++j) Xo[j] = X[8 + j];
    }
    float X1o[8];
    #pragma unroll
    for (int j = 0; j < 8; ++j) X1o[j] = Xo[j] + bo[h8 + j];
    #pragma unroll
    for (int dl = 0; dl < 8; ++dl) {
        const float a0 = at8[dl];
        #pragma unroll
        for (int j = 0; j < 8; ++j)
            X1o[j] += a0 * Wo[(h8 + dl) * DIM + h8 + j];
    }
    #pragma unroll
    for (int dl = 0; dl < 8; ++dl) {
        const float a1 = atO[dl];
        #pragma unroll
        for (int j = 0; j < 8; ++j)
            X1o[j] += a1 * Wo[(o8 + dl) * DIM + h8 + j];
    }

    // ---------------- exchange X1 halves ----------------
    __syncthreads();
    sbuf[tid]       = float4{X1o[0], X1o[1], X1o[2], X1o[3]};
    sbuf[256 + tid] = float4{X1o[4], X1o[5], X1o[6], X1o[7]};
    __syncthreads();
    const float4 xa = sbuf[tid ^ 64];
    const float4 xb = sbuf[256 + (tid ^ 64)];
    float X1p[8] = {xa.x, xa.y, xa.z, xa.w, xb.x, xb.y, xb.z, xb.w};

    // ---------------- FFN1: own 16 hidden units ----------------
    float hh[16];
    #pragma unroll
    for (int fl = 0; fl < 16; ++fl) hh[fl] = b1[f16 + fl];
    #pragma unroll
    for (int dl = 0; dl < 8; ++dl) {
        const float xd = X1o[dl];
        #pragma unroll
        for (int fl = 0; fl < 16; ++fl)
            hh[fl] += xd * W1[(h8 + dl) * FF + f16 + fl];
    }
    #pragma unroll
    for (int dl = 0; dl < 8; ++dl) {
        const float xd = X1p[dl];
        #pragma unroll
        for (int fl = 0; fl < 16; ++fl)
            hh[fl] += xd * W1[(o8 + dl) * FF + f16 + fl];
    }
    #pragma unroll
    for (int fl = 0; fl < 16; ++fl) hh[fl] = fmaxf(hh[fl], 0.f);

    // ---------------- FFN2: own partial + cross partial ----------------
    float X2o[8], Xc[8];
    #pragma unroll
    for (int j = 0; j < 8; ++j) { X2o[j] = X1o[j] + b2[h8 + j]; Xc[j] = 0.f; }
    #pragma unroll
    for (int fl = 0; fl < 16; ++fl) {
        const float hf = hh[fl];
        #pragma unroll
        for (int j = 0; j < 8; ++j) {
            X2o[j] += hf * W2[(f16 + fl) * DIM + h8 + j];
            Xc[j]  += hf * W2[(f16 + fl) * DIM + o8 + j];
        }
    }

    // ---------------- exchange cross partials, finish X2 ----------------
    __syncthreads();
    sbuf[tid]       = float4{Xc[0], Xc[1], Xc[2], Xc[3]};
    sbuf[256 + tid] = float4{Xc[4], Xc[5], Xc[6], Xc[7]};
    __syncthreads();
    const float4 ca = sbuf[tid ^ 64];
    const float4 cb = sbuf[256 + (tid ^ 64)];
    X2o[0] += ca.x; X2o[1] += ca.y; X2o[2] += ca.z; X2o[3] += ca.w;
    X2o[4] += cb.x; X2o[5] += cb.y; X2o[6] += cb.z; X2o[7] += cb.w;

    // ---------------- write own 8 floats of the X2 row ----------------
    float4* dst = (float4*)(xout + row * DIM + h8);
    dst[0] = float4{X2o[0], X2o[1], X2o[2], X2o[3]};
    dst[1] = float4{X2o[4], X2o[5], X2o[6], X2o[7]};
}

// ---------------------------------------------------------------------------
// Head: vocab GEMM [R,16] @ [16,256] + bias. Wave-uniform s_load of the X row,
// 1 col/lane, coalesced 256B stores. ~write-BW-bound (~49us).
// ---------------------------------------------------------------------------
#define ROWS_PER_BLOCK 32

__global__ __launch_bounds__(256) void head_kernel(
    const float* __restrict__ xin,
    const float* __restrict__ Wh,
    const float* __restrict__ bh,
    float* __restrict__ out)
{
    const int tid = threadIdx.x;
    const int col = tid;
    float wh[DIM];
    #pragma unroll
    for (int d = 0; d < DIM; ++d) wh[d] = Wh[d * VOCAB + col];
    const float bhv = bh[col];

    const size_t row0 = (size_t)blockIdx.x * ROWS_PER_BLOCK;
    #pragma unroll 4
    for (int r = 0; r < ROWS_PER_BLOCK; ++r) {
        const float* xr = xin + (row0 + r) * DIM;  // wave-uniform address
        float acc = bhv;
        #pragma unroll
        for (int d = 0; d < DIM; ++d) acc += xr[d] * wh[d];
        out[(row0 + r) * VOCAB + col] = acc;
    }
}

// ---------------------------------------------------------------------------
// Fallback (ws too small): single-pass per-row body + per-column head.
// ---------------------------------------------------------------------------
#define ITEMS_PER_BLOCK 32
#define ITEM_STRIDE 136

__global__ __launch_bounds__(256) void fused_fallback_kernel(
    const int* __restrict__ x,
    const float* __restrict__ token_embed,
    const float* __restrict__ pos_embed,
    const float* __restrict__ Wq, const float* __restrict__ bq,
    const float* __restrict__ Wk, const float* __restrict__ bk,
    const float* __restrict__ Wv, const float* __restrict__ bv,
    const float* __restrict__ Wo, const float* __restrict__ bo,
    const float* __restrict__ W1, const float* __restrict__ b1,
    const float* __restrict__ W2, const float* __restrict__ b2,
    const float* __restrict__ Wh, const float* __restrict__ bh,
    float* __restrict__ out)
{
    __shared__ float sK[ITEMS_PER_BLOCK * ITEM_STRIDE];
    __shared__ float sV[ITEMS_PER_BLOCK * ITEM_STRIDE];

    const int tid = threadIdx.x;
    const int i = tid >> 3;
    const int n = tid & 7;
    const int b = blockIdx.x * ITEMS_PER_BLOCK + i;

    float X[DIM];
    {
        const int idx = x[b * SEQ + n];
        const float4* te = (const float4*)(token_embed + idx * DIM);
        const float4* pe = (const float4*)(pos_embed + n * DIM);
        #pragma unroll
        for (int j = 0; j < 4; ++j) {
            float4 a = te[j];
            float4 p = pe[j];
            X[4*j+0] = a.x + p.x; X[4*j+1] = a.y + p.y;
            X[4*j+2] = a.z + p.z; X[4*j+3] = a.w + p.w;
        }
    }

    float Q[DIM], Kr[DIM], Vr[DIM];
    #pragma unroll
    for (int e = 0; e < DIM; ++e) {
        float qq = bq[e], kk = bk[e], vv = bv[e];
        #pragma unroll
        for (int d = 0; d < DIM; ++d) {
            qq += X[d] * Wq[d * DIM + e];
            kk += X[d] * Wk[d * DIM + e];
            vv += X[d] * Wv[d * DIM + e];
        }
        Q[e] = qq; Kr[e] = kk; Vr[e] = vv;
    }
    {
        float* kdst = sK + i * ITEM_STRIDE + n * DIM;
        float* vdst = sV + i * ITEM_STRIDE + n * DIM;
        #pragma unroll
        for (int j = 0; j < 4; ++j) {
            float4 kk, vv;
            kk.x = Kr[4*j+0]; kk.y = Kr[4*j+1]; kk.z = Kr[4*j+2]; kk.w = Kr[4*j+3];
            vv.x = Vr[4*j+0]; vv.y = Vr[4*j+1]; vv.z = Vr[4*j+2]; vv.w = Vr[4*j+3];
            ((float4*)kdst)[j] = kk;
            ((float4*)vdst)[j] = vv;
        }
    }
    __syncthreads();

    float sc[SEQ];
    #pragma unroll
    for (int m = 0; m < SEQ; ++m) {
        const float* kr = sK + i * ITEM_STRIDE + m * DIM;
        float s = 0.f;
        #pragma unroll
        for (int d = 0; d < DIM; ++d) s += Q[d] * kr[d];
        sc[m] = s * 0.25f;
    }
    float mx = sc[0];
    #pragma unroll
    for (int m = 1; m < SEQ; ++m) mx = fmaxf(mx, sc[m]);
    float sum = 0.f;
    #pragma unroll
    for (int m = 0; m < SEQ; ++m) { sc[m] = __expf(sc[m] - mx); sum += sc[m]; }
    const float inv = 1.0f / sum;

    float at[DIM];
    #pragma unroll
    for (int d = 0; d < DIM; ++d) at[d] = 0.f;
    #pragma unroll
    for (int m = 0; m < SEQ; ++m) {
        const float w = sc[m] * inv;
        const float* vr = sV + i * ITEM_STRIDE + m * DIM;
        #pragma unroll
        for (int d = 0; d < DIM; ++d) at[d] += w * vr[d];
    }

    float X1[DIM];
    #pragma unroll
    for (int e = 0; e < DIM; ++e) {
        float o = bo[e];
        #pragma unroll
        for (int d = 0; d < DIM; ++d) o += at[d] * Wo[d * DIM + e];
        X1[e] = X[e] + o;
    }
    float h[FF];
    #pragma unroll
    for (int f = 0; f < FF; ++f) {
        float a = b1[f];
        #pragma unroll
        for (int d = 0; d < DIM; ++d) a += X1[d] * W1[d * FF + f];
        h[f] = fmaxf(a, 0.f);
    }
    float X2[DIM];
    #pragma unroll
    for (int e = 0; e < DIM; ++e) {
        float a = b2[e];
        #pragma unroll
        for (int f = 0; f < FF; ++f) a += h[f] * W2[f * DIM + e];
        X2[e] = X1[e] + a;
    }

    __syncthreads();
    {
        float* xdst = sK + i * ITEM_STRIDE + n * DIM;
        #pragma unroll
        for (int j = 0; j < 4; ++j) {
            float4 xx;
            xx.x = X2[4*j+0]; xx.y = X2[4*j+1]; xx.z = X2[4*j+2]; xx.w = X2[4*j+3];
            ((float4*)xdst)[j] = xx;
        }
    }
    __syncthreads();

    float wh[DIM];
    #pragma unroll
    for (int d = 0; d < DIM; ++d) wh[d] = Wh[d * VOCAB + tid];
    const float bhv = bh[tid];

    const size_t obase = (size_t)blockIdx.x * (ITEMS_PER_BLOCK * SEQ) * VOCAB + tid;
    #pragma unroll 4
    for (int r = 0; r < ITEMS_PER_BLOCK * SEQ; ++r) {
        const float* xr = sK + (r >> 3) * ITEM_STRIDE + (r & 7) * DIM;
        float acc = bhv;
        #pragma unroll
        for (int d = 0; d < DIM; ++d) acc += xr[d] * wh[d];
        out[obase + (size_t)r * VOCAB] = acc;
    }
}

extern "C" void kernel_launch(void* const* d_in, const int* in_sizes, int n_in,
                              void* d_out, int out_size, void* d_ws, size_t ws_size,
                              hipStream_t stream) {
    const int*   x           = (const int*)  d_in[0];
    const float* token_embed = (const float*)d_in[1];
    const float* pos_embed   = (const float*)d_in[2];
    const float* Wq = (const float*)d_in[3];
    const float* bq = (const float*)d_in[4];
    const float* Wk = (const float*)d_in[5];
    const float* bk = (const float*)d_in[6];
    const float* Wv = (const float*)d_in[7];
    const float* bv = (const float*)d_in[8];
    const float* Wo = (const float*)d_in[9];
    const float* bo = (const float*)d_in[10];
    const float* W1 = (const float*)d_in[11];
    const float* b1 = (const float*)d_in[12];
    const float* W2 = (const float*)d_in[13];
    const float* b2 = (const float*)d_in[14];
    const float* Wh = (const float*)d_in[15];
    const float* bh = (const float*)d_in[16];
    float* out = (float*)d_out;

    const int B = in_sizes[0] / SEQ;                 // 32768
    const int nrows = B * SEQ;                       // 262144
    const size_t ws_needed = (size_t)nrows * DIM * sizeof(float);  // 16 MB

    if (ws_size >= ws_needed) {
        float* xws = (float*)d_ws;
        // 16 items (128 rows) per block, 2 threads per row -> 2048 blocks
        body_kernel<<<B / 16, 256, 0, stream>>>(
            x, token_embed, pos_embed, Wq, bq, Wk, bk, Wv, bv, Wo, bo,
            W1, b1, W2, b2, xws);
        head_kernel<<<nrows / ROWS_PER_BLOCK, 256, 0, stream>>>(
            xws, Wh, bh, out);
    } else {
        fused_fallback_kernel<<<B / ITEMS_PER_BLOCK, 256, 0, stream>>>(
            x, token_embed, pos_embed, Wq, bq, Wk, bk, Wv, bv, Wo, bo,
            W1, b1, W2, b2, Wh, bh, out);
    }
}

// Round 7
// 172.846 us; speedup vs baseline: 2.8955x; 2.8955x over previous
//
#include <hip/hip_runtime.h>

#define SEQ 8
#define DIM 16
#define FF 32
#define VOCAB 256

// ds_swizzle XOR butterfly on a float (src_lane = lane ^ T, T<8 stays within
// the 8-lane item group). BitMode offset = (xor<<10) | (or<<5) | and, and=0x1F.
#define SWZF(val, imm) __int_as_float(__builtin_amdgcn_ds_swizzle(__float_as_int(val), (imm)))

// LDS weight layout (dword offsets), all 16B-aligned:
// Wq 0, Wk 256, Wv 512, Wo 768, W1 1024 (512), W2 1536 (512),
// bq 2048, bk 2064, bv 2080, bo 2096, b1 2112 (32), b2 2144 (16) -> 2160 total
#define LW_WQ 0
#define LW_WK 256
#define LW_WV 512
#define LW_WO 768
#define LW_W1 1024
#define LW_W2 1536
#define LW_BQ 2048
#define LW_BK 2064
#define LW_BV 2080
#define LW_BO 2096
#define LW_B1 2112
#define LW_B2 2144
#define LW_TOT 2160

// ---------------------------------------------------------------------------
// Body v4 = round-4 swizzle body (1 row/thread, 48us) + LDS-staged weights.
// Theory: round-4 was serialized on each wave's redundant ~470-chunk s_load
// weight stream (~245cyc L2 latency each ~= 48us). Staging weights in LDS
// turns weight reads into broadcast ds_reads that pipeline in the lgkm queue.
// K/V row exchange stays the ds_swizzle XOR butterfly (no barriers).
// ---------------------------------------------------------------------------
__global__ __launch_bounds__(256, 4) void body_kernel(
    const int* __restrict__ x,
    const float* __restrict__ token_embed,
    const float* __restrict__ pos_embed,
    const float* __restrict__ Wq, const float* __restrict__ bq,
    const float* __restrict__ Wk, const float* __restrict__ bk,
    const float* __restrict__ Wv, const float* __restrict__ bv,
    const float* __restrict__ Wo, const float* __restrict__ bo,
    const float* __restrict__ W1, const float* __restrict__ b1,
    const float* __restrict__ W2, const float* __restrict__ b2,
    float* __restrict__ xout)
{
    __shared__ float sW[LW_TOT];

    const int tid = threadIdx.x;

    // ---------------- stage all weights + biases into LDS ----------------
    sW[LW_WQ + tid] = Wq[tid];
    sW[LW_WK + tid] = Wk[tid];
    sW[LW_WV + tid] = Wv[tid];
    sW[LW_WO + tid] = Wo[tid];
    sW[LW_W1 + tid]       = W1[tid];
    sW[LW_W1 + 256 + tid] = W1[256 + tid];
    sW[LW_W2 + tid]       = W2[tid];
    sW[LW_W2 + 256 + tid] = W2[256 + tid];
    if (tid < 112) {
        float v;
        if      (tid < 16) v = bq[tid];
        else if (tid < 32) v = bk[tid - 16];
        else if (tid < 48) v = bv[tid - 32];
        else if (tid < 64) v = bo[tid - 48];
        else if (tid < 96) v = b1[tid - 64];
        else               v = b2[tid - 96];
        sW[LW_BQ + tid] = v;
    }
    __syncthreads();

    const float* sWq = sW + LW_WQ;
    const float* sWk = sW + LW_WK;
    const float* sWv = sW + LW_WV;
    const float* sWo = sW + LW_WO;
    const float* sW1 = sW + LW_W1;
    const float* sW2 = sW + LW_W2;
    const float* sbq = sW + LW_BQ;
    const float* sbk = sW + LW_BK;
    const float* sbv = sW + LW_BV;
    const float* sbo = sW + LW_BO;
    const float* sb1 = sW + LW_B1;
    const float* sb2 = sW + LW_B2;

    const int n = tid & 7;                                   // seq position
    const size_t row = (size_t)blockIdx.x * 256 + tid;       // global row id

    // ---------------- embedding + positional ----------------
    float X[DIM];
    {
        const int idx = x[row];
        const float4* te = (const float4*)(token_embed + (size_t)idx * DIM);
        const float4* pe = (const float4*)(pos_embed + n * DIM);
        #pragma unroll
        for (int j = 0; j < 4; ++j) {
            float4 a = te[j];
            float4 p = pe[j];
            X[4*j+0] = a.x + p.x;
            X[4*j+1] = a.y + p.y;
            X[4*j+2] = a.z + p.z;
            X[4*j+3] = a.w + p.w;
        }
    }

    // ---------------- QKV: outer-product over d, 48 acc chains ----------------
    float q[DIM], k[DIM], v[DIM];
    #pragma unroll
    for (int e = 0; e < DIM; ++e) { q[e] = sbq[e]; k[e] = sbk[e]; v[e] = sbv[e]; }
    #pragma unroll
    for (int d = 0; d < DIM; ++d) {
        const float xd = X[d];
        #pragma unroll
        for (int e = 0; e < DIM; ++e) {
            q[e] += xd * sWq[d * DIM + e];
            k[e] += xd * sWk[d * DIM + e];
            v[e] += xd * sWv[d * DIM + e];
        }
    }

    // ---------------- attention scores via XOR butterfly ----------------
    float sc[SEQ];
    {
        float s = 0.f;
        #pragma unroll
        for (int d = 0; d < DIM; ++d) s += q[d] * k[d];      // t = 0 (self)
        sc[0] = s * 0.25f;
    }
    #define SCORE_PHASE(T, IMM)                                   \
    {                                                             \
        float s = 0.f;                                            \
        _Pragma("unroll")                                         \
        for (int d = 0; d < DIM; ++d) s += q[d] * SWZF(k[d], IMM);\
        sc[T] = s * 0.25f;                                        \
    }
    SCORE_PHASE(1, 0x041F)
    SCORE_PHASE(2, 0x081F)
    SCORE_PHASE(3, 0x0C1F)
    SCORE_PHASE(4, 0x101F)
    SCORE_PHASE(5, 0x141F)
    SCORE_PHASE(6, 0x181F)
    SCORE_PHASE(7, 0x1C1F)
    #undef SCORE_PHASE

    // ---------------- softmax over the 8 scores (per-lane) ----------------
    float mx = sc[0];
    #pragma unroll
    for (int m = 1; m < SEQ; ++m) mx = fmaxf(mx, sc[m]);
    float sum = 0.f;
    float w[SEQ];
    #pragma unroll
    for (int m = 0; m < SEQ; ++m) { w[m] = __expf(sc[m] - mx); sum += w[m]; }
    const float inv = 1.0f / sum;
    #pragma unroll
    for (int m = 0; m < SEQ; ++m) w[m] *= inv;

    // ---------------- PV via XOR butterfly ----------------
    float at[DIM];
    #pragma unroll
    for (int d = 0; d < DIM; ++d) at[d] = w[0] * v[d];       // t = 0 (self)
    #define PV_PHASE(T, IMM)                                      \
    {                                                             \
        const float wt = w[T];                                    \
        _Pragma("unroll")                                         \
        for (int d = 0; d < DIM; ++d) at[d] += wt * SWZF(v[d], IMM);\
    }
    PV_PHASE(1, 0x041F)
    PV_PHASE(2, 0x081F)
    PV_PHASE(3, 0x0C1F)
    PV_PHASE(4, 0x101F)
    PV_PHASE(5, 0x141F)
    PV_PHASE(6, 0x181F)
    PV_PHASE(7, 0x1C1F)
    #undef PV_PHASE

    // ---------------- O projection + residual ----------------
    float X1[DIM];
    #pragma unroll
    for (int e = 0; e < DIM; ++e) X1[e] = X[e] + sbo[e];
    #pragma unroll
    for (int d = 0; d < DIM; ++d) {
        const float ad = at[d];
        #pragma unroll
        for (int e = 0; e < DIM; ++e) X1[e] += ad * sWo[d * DIM + e];
    }

    // ---------------- FFN + residual ----------------
    float h[FF];
    #pragma unroll
    for (int f = 0; f < FF; ++f) h[f] = sb1[f];
    #pragma unroll
    for (int d = 0; d < DIM; ++d) {
        const float xd = X1[d];
        #pragma unroll
        for (int f = 0; f < FF; ++f) h[f] += xd * sW1[d * FF + f];
    }
    #pragma unroll
    for (int f = 0; f < FF; ++f) h[f] = fmaxf(h[f], 0.f);

    float X2[DIM];
    #pragma unroll
    for (int e = 0; e < DIM; ++e) X2[e] = X1[e] + sb2[e];
    #pragma unroll
    for (int f = 0; f < FF; ++f) {
        const float hf = h[f];
        #pragma unroll
        for (int e = 0; e < DIM; ++e) X2[e] += hf * sW2[f * DIM + e];
    }

    // ---------------- write X2 row ----------------
    float4* dst = (float4*)(xout + row * DIM);
    #pragma unroll
    for (int j = 0; j < 4; ++j) {
        float4 xx;
        xx.x = X2[4*j+0]; xx.y = X2[4*j+1]; xx.z = X2[4*j+2]; xx.w = X2[4*j+3];
        dst[j] = xx;
    }
}

// ---------------------------------------------------------------------------
// Head v2: vocab GEMM [R,16] @ [16,256] + bias. Lane owns 4 cols (64 lanes x
// 4 = full 256-col row), so each wave emits ONE global_store_dwordx4 per row
// (1KB/wave-store) and ONE wave-uniform s_load of the X row. 4x fewer store
// and s_load instructions than the 1-col/lane version. wh4[16] = 64 VGPR is
// fine here: standalone kernel, ~90 VGPR -> 5 waves/SIMD, 8k waves queued.
// ---------------------------------------------------------------------------
#define HROWS 128   // rows per block (4 waves x 32 rows)

__global__ __launch_bounds__(256) void head_kernel(
    const float* __restrict__ xin,
    const float* __restrict__ Wh,
    const float* __restrict__ bh,
    float* __restrict__ out)
{
    const int tid = threadIdx.x;
    const int w = tid >> 6;
    const int l = tid & 63;
    const int c4 = 4 * l;

    float4 wh4[DIM];
    #pragma unroll
    for (int d = 0; d < DIM; ++d)
        wh4[d] = *(const float4*)(Wh + d * VOCAB + c4);
    const float4 bh4 = *(const float4*)(bh + c4);

    const size_t row0 = (size_t)blockIdx.x * HROWS + w * (HROWS / 4);
    #pragma unroll 4
    for (int r = 0; r < HROWS / 4; ++r) {
        const float* xr = xin + (row0 + r) * DIM;   // wave-uniform address
        float4 acc = bh4;
        #pragma unroll
        for (int d = 0; d < DIM; ++d) {
            const float xv = xr[d];
            acc.x += xv * wh4[d].x;
            acc.y += xv * wh4[d].y;
            acc.z += xv * wh4[d].z;
            acc.w += xv * wh4[d].w;
        }
        *(float4*)(out + (row0 + r) * VOCAB + c4) = acc;
    }
}

// ---------------------------------------------------------------------------
// Fallback (ws too small): single-pass per-row body + per-column head.
// ---------------------------------------------------------------------------
#define ITEMS_PER_BLOCK 32
#define ITEM_STRIDE 136

__global__ __launch_bounds__(256) void fused_fallback_kernel(
    const int* __restrict__ x,
    const float* __restrict__ token_embed,
    const float* __restrict__ pos_embed,
    const float* __restrict__ Wq, const float* __restrict__ bq,
    const float* __restrict__ Wk, const float* __restrict__ bk,
    const float* __restrict__ Wv, const float* __restrict__ bv,
    const float* __restrict__ Wo, const float* __restrict__ bo,
    const float* __restrict__ W1, const float* __restrict__ b1,
    const float* __restrict__ W2, const float* __restrict__ b2,
    const float* __restrict__ Wh, const float* __restrict__ bh,
    float* __restrict__ out)
{
    __shared__ float sK[ITEMS_PER_BLOCK * ITEM_STRIDE];
    __shared__ float sV[ITEMS_PER_BLOCK * ITEM_STRIDE];

    const int tid = threadIdx.x;
    const int i = tid >> 3;
    const int n = tid & 7;
    const int b = blockIdx.x * ITEMS_PER_BLOCK + i;

    float X[DIM];
    {
        const int idx = x[b * SEQ + n];
        const float4* te = (const float4*)(token_embed + idx * DIM);
        const float4* pe = (const float4*)(pos_embed + n * DIM);
        #pragma unroll
        for (int j = 0; j < 4; ++j) {
            float4 a = te[j];
            float4 p = pe[j];
            X[4*j+0] = a.x + p.x; X[4*j+1] = a.y + p.y;
            X[4*j+2] = a.z + p.z; X[4*j+3] = a.w + p.w;
        }
    }

    float Q[DIM], Kr[DIM], Vr[DIM];
    #pragma unroll
    for (int e = 0; e < DIM; ++e) {
        float qq = bq[e], kk = bk[e], vv = bv[e];
        #pragma unroll
        for (int d = 0; d < DIM; ++d) {
            qq += X[d] * Wq[d * DIM + e];
            kk += X[d] * Wk[d * DIM + e];
            vv += X[d] * Wv[d * DIM + e];
        }
        Q[e] = qq; Kr[e] = kk; Vr[e] = vv;
    }
    {
        float* kdst = sK + i * ITEM_STRIDE + n * DIM;
        float* vdst = sV + i * ITEM_STRIDE + n * DIM;
        #pragma unroll
        for (int j = 0; j < 4; ++j) {
            float4 kk, vv;
            kk.x = Kr[4*j+0]; kk.y = Kr[4*j+1]; kk.z = Kr[4*j+2]; kk.w = Kr[4*j+3];
            vv.x = Vr[4*j+0]; vv.y = Vr[4*j+1]; vv.z = Vr[4*j+2]; vv.w = Vr[4*j+3];
            ((float4*)kdst)[j] = kk;
            ((float4*)vdst)[j] = vv;
        }
    }
    __syncthreads();

    float sc[SEQ];
    #pragma unroll
    for (int m = 0; m < SEQ; ++m) {
        const float* kr = sK + i * ITEM_STRIDE + m * DIM;
        float s = 0.f;
        #pragma unroll
        for (int d = 0; d < DIM; ++d) s += Q[d] * kr[d];
        sc[m] = s * 0.25f;
    }
    float mx = sc[0];
    #pragma unroll
    for (int m = 1; m < SEQ; ++m) mx = fmaxf(mx, sc[m]);
    float sum = 0.f;
    #pragma unroll
    for (int m = 0; m < SEQ; ++m) { sc[m] = __expf(sc[m] - mx); sum += sc[m]; }
    const float inv = 1.0f / sum;

    float at[DIM];
    #pragma unroll
    for (int d = 0; d < DIM; ++d) at[d] = 0.f;
    #pragma unroll
    for (int m = 0; m < SEQ; ++m) {
        const float w = sc[m] * inv;
        const float* vr = sV + i * ITEM_STRIDE + m * DIM;
        #pragma unroll
        for (int d = 0; d < DIM; ++d) at[d] += w * vr[d];
    }

    float X1[DIM];
    #pragma unroll
    for (int e = 0; e < DIM; ++e) {
        float o = bo[e];
        #pragma unroll
        for (int d = 0; d < DIM; ++d) o += at[d] * Wo[d * DIM + e];
        X1[e] = X[e] + o;
    }
    float h[FF];
    #pragma unroll
    for (int f = 0; f < FF; ++f) {
        float a = b1[f];
        #pragma unroll
        for (int d = 0; d < DIM; ++d) a += X1[d] * W1[d * FF + f];
        h[f] = fmaxf(a, 0.f);
    }
    float X2[DIM];
    #pragma unroll
    for (int e = 0; e < DIM; ++e) {
        float a = b2[e];
        #pragma unroll
        for (int f = 0; f < FF; ++f) a += h[f] * W2[f * DIM + e];
        X2[e] = X1[e] + a;
    }

    __syncthreads();
    {
        float* xdst = sK + i * ITEM_STRIDE + n * DIM;
        #pragma unroll
        for (int j = 0; j < 4; ++j) {
            float4 xx;
            xx.x = X2[4*j+0]; xx.y = X2[4*j+1]; xx.z = X2[4*j+2]; xx.w = X2[4*j+3];
            ((float4*)xdst)[j] = xx;
        }
    }
    __syncthreads();

    float wh[DIM];
    #pragma unroll
    for (int d = 0; d < DIM; ++d) wh[d] = Wh[d * VOCAB + tid];
    const float bhv = bh[tid];

    const size_t obase = (size_t)blockIdx.x * (ITEMS_PER_BLOCK * SEQ) * VOCAB + tid;
    #pragma unroll 4
    for (int r = 0; r < ITEMS_PER_BLOCK * SEQ; ++r) {
        const float* xr = sK + (r >> 3) * ITEM_STRIDE + (r & 7) * DIM;
        float acc = bhv;
        #pragma unroll
        for (int d = 0; d < DIM; ++d) acc += xr[d] * wh[d];
        out[obase + (size_t)r * VOCAB] = acc;
    }
}

extern "C" void kernel_launch(void* const* d_in, const int* in_sizes, int n_in,
                              void* d_out, int out_size, void* d_ws, size_t ws_size,
                              hipStream_t stream) {
    const int*   x           = (const int*)  d_in[0];
    const float* token_embed = (const float*)d_in[1];
    const float* pos_embed   = (const float*)d_in[2];
    const float* Wq = (const float*)d_in[3];
    const float* bq = (const float*)d_in[4];
    const float* Wk = (const float*)d_in[5];
    const float* bk = (const float*)d_in[6];
    const float* Wv = (const float*)d_in[7];
    const float* bv = (const float*)d_in[8];
    const float* Wo = (const float*)d_in[9];
    const float* bo = (const float*)d_in[10];
    const float* W1 = (const float*)d_in[11];
    const float* b1 = (const float*)d_in[12];
    const float* W2 = (const float*)d_in[13];
    const float* b2 = (const float*)d_in[14];
    const float* Wh = (const float*)d_in[15];
    const float* bh = (const float*)d_in[16];
    float* out = (float*)d_out;

    const int B = in_sizes[0] / SEQ;                 // 32768
    const int nrows = B * SEQ;                       // 262144
    const size_t ws_needed = (size_t)nrows * DIM * sizeof(float);  // 16 MB

    if (ws_size >= ws_needed) {
        float* xws = (float*)d_ws;
        body_kernel<<<nrows / 256, 256, 0, stream>>>(
            x, token_embed, pos_embed, Wq, bq, Wk, bk, Wv, bv, Wo, bo,
            W1, b1, W2, b2, xws);
        head_kernel<<<nrows / HROWS, 256, 0, stream>>>(
            xws, Wh, bh, out);
    } else {
        fused_fallback_kernel<<<B / ITEMS_PER_BLOCK, 256, 0, stream>>>(
            x, token_embed, pos_embed, Wq, bq, Wk, bk, Wv, bv, Wo, bo,
            W1, b1, W2, b2, Wh, bh, out);
    }
}